// Round 6
// baseline (123.382 us; speedup 1.0000x reference)
//
#include <hip/hip_runtime.h>
#include <hip/hip_bf16.h>

typedef __bf16 bf16x8 __attribute__((ext_vector_type(8)));
typedef __bf16 bf16x4 __attribute__((ext_vector_type(4)));
typedef short  s16x4  __attribute__((ext_vector_type(4)));
typedef float  f32x4  __attribute__((ext_vector_type(4)));

#define MFMA32(a, b, c) __builtin_amdgcn_mfma_f32_16x16x32_bf16((a), (b), (c), 0, 0, 0)
#define MFMA16K(a, b, c) __builtin_amdgcn_mfma_f32_16x16x16bf16_1k((a), (b), (c), 0, 0, 0)

#if __has_builtin(__builtin_amdgcn_exp2f)
#define EXP2F(x) __builtin_amdgcn_exp2f(x)
#else
#define EXP2F(x) __expf(0.6931471805599453f * (x))
#endif

// async global->LDS, 16B per lane. LDS dest must be wave-uniform base.
#define GL16(G, L)                                                            \
    __builtin_amdgcn_global_load_lds(                                         \
        (const __attribute__((address_space(1))) void*)(G),                   \
        (__attribute__((address_space(3))) void*)(L), 16, 0, 0)

#define SPLIT 8
// BS=4, C=128, L=4096, D=64. Q pre-scaled by 0.125*log2(e): softmax in base 2.
// Fixed-bound softmax: p = 2^(s - BBOUND); the 2^(m-B) factor cancels in the
// final normalization. BBOUND folded into QK MFMA accumulator init.
#define QSCALE 0.18033688011112042f
#define BBOUND 12.0f

// K workspace layout (MFMA-permuted, per 64-key tile contiguous 8 KB):
//   Kp[b][kt][nt][half][quad][l15][i]  (key = nt*16+l15, d = half*32+quad*8+i)
// V workspace layout (permuted, per 64-key tile contiguous 8 KB):
//   Vp[b][kt][d][quad][kc][i]  (quad=key>>2&3, kc=key>>4, i=key&3)
// Wqkv_b: [msel][64][128] bf16 row-major (linear cast of Wq|Wk|Wv)
// Wo_b:   [128][64] bf16 row-major (linear cast of Wo)

// ---------------------------------------------------------------------------
// Kernel 0: one-time weight cast f32 -> bf16 (linear copy). 32768 elements.
// ---------------------------------------------------------------------------
__global__ __launch_bounds__(256) void wprep_kernel(
    const float* __restrict__ Wq, const float* __restrict__ Wk,
    const float* __restrict__ Wv, const float* __restrict__ Wo,
    __bf16* __restrict__ Wqkv_b, __bf16* __restrict__ Wo_b)
{
    const int idx = (blockIdx.x * 256 + threadIdx.x) * 4;   // 32 blocks
    const float* src;
    __bf16* dst;
    if (idx < 8192)       { src = Wq + idx;         dst = Wqkv_b + idx; }
    else if (idx < 16384) { src = Wk + idx - 8192;  dst = Wqkv_b + idx; }
    else if (idx < 24576) { src = Wv + idx - 16384; dst = Wqkv_b + idx; }
    else                  { src = Wo + idx - 24576; dst = Wo_b + idx - 24576; }
    float4 v = *(const float4*)src;
    bf16x4 o;
    o[0] = (__bf16)v.x; o[1] = (__bf16)v.y;
    o[2] = (__bf16)v.z; o[3] = (__bf16)v.w;
    *(bf16x4*)dst = o;
}

// ---------------------------------------------------------------------------
// Kernel 1: QKV projection, bf16 MFMA. grid = 256 (b x 64 tiles of 64 tok).
// (byte-identical to round 5)
// ---------------------------------------------------------------------------
__global__ __launch_bounds__(256, 4) void qkv_kernel(
    const float* __restrict__ inpt,
    const float* __restrict__ bq, const float* __restrict__ bk,
    const float* __restrict__ bv,
    const __bf16* __restrict__ Wqkv_b,
    __bf16* __restrict__ Qws, __bf16* __restrict__ Kws, __bf16* __restrict__ VTws)
{
    __shared__ __align__(16) __bf16 xT[64 * 136];   // [tok][c]
    __shared__ __align__(16) __bf16 os[64 * 136];   // [tok][qk-out 0..127]
    const int bid = blockIdx.x;
    const int b   = bid >> 6;
    const int l0  = (bid & 63) << 6;                // 64 tokens
    const int t   = threadIdx.x;

    // stage x^T: thread (c = t>>1, half = t&1) loads 32 floats of row c
    {
        const int c = t >> 1, half = t & 1;
        const float* xin = inpt + ((size_t)(b * 128 + c)) * 4096 + l0 + half * 32;
        #pragma unroll
        for (int i = 0; i < 8; ++i) {
            float4 v = *(const float4*)(xin + i * 4);
            const int tok = half * 32 + i * 4;
            xT[(tok + 0) * 136 + c] = (__bf16)v.x;
            xT[(tok + 1) * 136 + c] = (__bf16)v.y;
            xT[(tok + 2) * 136 + c] = (__bf16)v.z;
            xT[(tok + 3) * 136 + c] = (__bf16)v.w;
        }
    }
    __syncthreads();

    const int w    = t >> 6;
    const int lane = t & 63;
    const int quad = lane >> 4;
    const int l15  = lane & 15;

    f32x4 acc[12];
    #pragma unroll
    for (int j = 0; j < 12; ++j)
        #pragma unroll
        for (int r = 0; r < 4; ++r) acc[j][r] = 0.f;

    #pragma unroll
    for (int ks = 0; ks < 4; ++ks) {
        bf16x8 af = *(const bf16x8*)&xT[(w * 16 + l15) * 136 + ks * 32 + quad * 8];
        #pragma unroll
        for (int j = 0; j < 12; ++j) {
            bf16x8 bf = *(const bf16x8*)(Wqkv_b + j * 2048 + l15 * 128
                                         + ks * 32 + quad * 8);
            acc[j] = MFMA32(af, bf, acc[j]);        // D[m=tok][n=out]
        }
    }

    // epilogue: D rows (quad*4+r) = token (within wave's 16), col l15 = out
    #pragma unroll
    for (int j = 0; j < 12; ++j) {
        const int msel = j >> 2;
        const int o0   = (j & 3) * 16;
        const float* bb = (msel == 0) ? bq : ((msel == 1) ? bk : bv);
        float bias = bb[o0 + l15];
        if (msel < 2) {
            const float scl = (msel == 0) ? QSCALE : 1.0f;
            const int oc = j * 16 + l15;            // 0..127
            #pragma unroll
            for (int r = 0; r < 4; ++r)
                os[(w * 16 + quad * 4 + r) * 136 + oc]
                    = (__bf16)((acc[j][r] + bias) * scl);
        } else {
            // permuted V store: key = w*16 + quad*4 + r within the block's
            // single 64-key tile -> kc = w, quad_v = quad, i = r.
            const int d  = o0 + l15;
            const int kt = bid & 63;
            bf16x4 v;
            #pragma unroll
            for (int r = 0; r < 4; ++r) v[r] = (__bf16)(acc[j][r] + bias);
            *(bf16x4*)(VTws + (size_t)b * 262144 + kt * 4096
                       + d * 64 + quad * 16 + w * 4) = v;
        }
    }
    __syncthreads();

    // Q store coalesced [l][64]; K store to the MFMA-permuted tile layout.
    // 1024 16B-chunks: chunk cid -> tok = cid>>4, c8 = cid&15 (c8<8 -> Q).
    #pragma unroll
    for (int g = 0; g < 4; ++g) {
        const int cid = t + g * 256;
        const int tok = cid >> 4, c8 = cid & 15;
        bf16x8 v = *(const bf16x8*)&os[tok * 136 + c8 * 8];
        if (c8 < 8) {
            *(bf16x8*)(Qws + ((size_t)(b * 4096 + l0 + tok)) * 64 + c8 * 8) = v;
        } else {
            const int d8 = c8 - 8;                  // d = d8*8 .. +7
            __bf16* dst = Kws + (size_t)b * 262144
                + (bid & 63) * 4096           // tile
                + (tok >> 4) * 1024           // nt subtile
                + (d8 >> 2) * 512             // half = d>>5
                + (d8 & 3) * 128              // quad = (d>>3)&3
                + (tok & 15) * 8;             // l15 = key&15
            *(bf16x8*)dst = v;
        }
    }
}

// ---------------------------------------------------------------------------
// Kernel 2: flash attention, split-K, fixed-bound softmax (no online max).
// NEW this round: 2-wave blocks (128 threads), each wave owns 64 q-rows (4
// subtiles of 16). The same 16 LDS fragment reads per tile now feed 96
// MFMAs instead of 48 -> LDS-read pipe work per unit of output halves, and
// per-wave MFMA ILP doubles. Grid stays 1024 blocks (4 blocks/CU, 8
// waves/CU at <=256 VGPR). Ring-2 K+V LDS (32 KB), vmcnt(0)+s_barrier
// pipeline, XCD-chunked bid swizzle, setprio around PV - all unchanged.
// grid = SPLIT x 128; block = 128 q (wave owns 64), 8 k-tiles of 64 keys.
// ---------------------------------------------------------------------------
__global__ __launch_bounds__(128, 2) void attn_kernel(
    const __bf16* __restrict__ Qws, const __bf16* __restrict__ Kws,
    const __bf16* __restrict__ VTws,
    __bf16* __restrict__ Ops, float* __restrict__ Lws)
{
    // [slot][0..4096) = K tile, [slot][4096..8192) = V tile
    __shared__ __align__(16) __bf16 sbuf[2][8192];

    const int bid0  = blockIdx.x;
    // XCD-chunked swizzle (bijective, 1024 % 8 == 0): XCD x owns split x.
    const int bid   = (bid0 & 7) * 128 + (bid0 >> 3);
    const int split = bid >> 7;
    const int qi    = bid & 127;
    const int b  = qi >> 5;
    const int l0 = (qi & 31) << 7;     // 128 q-rows per block
    const int t    = threadIdx.x;
    const int w    = t >> 6;           // wave 0/1
    const int lane = t & 63;
    const int quad = lane >> 4;
    const int l15  = lane & 15;

    // Q fragments for 4 subtiles (rows l0 + w*64 + qs*16 + l15), pre-scaled
    bf16x8 qf[4][2];
    #pragma unroll
    for (int qs = 0; qs < 4; ++qs) {
        const __bf16* qptr = Qws
            + ((size_t)(b * 4096 + l0 + w * 64 + qs * 16 + l15)) * 64 + quad * 8;
        qf[qs][0] = *(const bf16x8*)qptr;
        qf[qs][1] = *(const bf16x8*)(qptr + 32);
    }

    f32x4 cfr[4][4];
    #pragma unroll
    for (int qs = 0; qs < 4; ++qs)
        #pragma unroll
        for (int mt = 0; mt < 4; ++mt)
            #pragma unroll
            for (int r = 0; r < 4; ++r) cfr[qs][mt][r] = 0.f;
    float l_acc[4] = {0.f, 0.f, 0.f, 0.f};

    // hoisted V LDS element offsets (within V half of slot)
    int voff[8];
    #pragma unroll
    for (int mt = 0; mt < 4; ++mt) {
        const int d = mt * 16 + l15;
        #pragma unroll
        for (int kc8 = 0; kc8 < 2; ++kc8)
            voff[kc8 * 4 + mt] = d * 64 + (((2 * quad + kc8) ^ (d & 7)) * 8);
    }

    // staging source pointers (per-thread); LDS dests wave-uniform.
    // V source swizzle: chunk n -> src chunk (n>>3)*8 + ((n&7)^((n>>3)&7));
    // with n = g*128 + t the g-term drops out of the XOR (g*16 ≡ 0 mod 8).
    const uint4* Vg = (const uint4*)(VTws + ((size_t)b << 18));
    const int rw = t >> 3, cw = (t & 7) ^ ((t >> 3) & 7);
    const uint4* vbase = Vg + rw * 8 + cw + split * 4096;   // swizzled source
    const uint4* kbase = (const uint4*)(Kws + ((size_t)b << 18))
                       + t + split * 4096;                  // linear source

    union B4 { bf16x4 h; s16x4 s; };
    union V8 { bf16x8 v; s16x4 q[2]; };

    auto stage = [&](int kt, int slot) {                    // 8 GL16 / thread
        __bf16* Kd = &sbuf[slot][0];
        __bf16* Vd = &sbuf[slot][4096];
        const uint4* kp = kbase + (size_t)kt * 512;
        const uint4* vp = vbase + (size_t)kt * 512;
        #pragma unroll
        for (int g = 0; g < 4; ++g) {
            GL16(kp + g * 128, Kd + g * 1024 + w * 512);
            GL16(vp + g * 128, Vd + g * 1024 + w * 512);
        }
    };

    auto tile_step = [&](int slot) {
        const __bf16* Kb = &sbuf[slot][0];
        const __bf16* Vb = &sbuf[slot][4096];
        // ---- QK^T: K frags from LDS, shared across all 4 q-subtiles ------
        B4 pk[4][4];
        #pragma unroll
        for (int nt = 0; nt < 4; ++nt) {
            bf16x8 k0 = *(const bf16x8*)(Kb + nt * 1024 +       lane * 8);
            bf16x8 k1 = *(const bf16x8*)(Kb + nt * 1024 + 512 + lane * 8);
            #pragma unroll
            for (int qs = 0; qs < 4; ++qs) {
                f32x4 a = {-BBOUND, -BBOUND, -BBOUND, -BBOUND};
                a = MFMA32(k0, qf[qs][0], a);
                a = MFMA32(k1, qf[qs][1], a);
                float p0 = EXP2F(a[0]), p1 = EXP2F(a[1]);
                float p2 = EXP2F(a[2]), p3 = EXP2F(a[3]);
                pk[qs][nt].h[0] = (__bf16)p0; pk[qs][nt].h[1] = (__bf16)p1;
                pk[qs][nt].h[2] = (__bf16)p2; pk[qs][nt].h[3] = (__bf16)p3;
                l_acc[qs] += (p0 + p1) + (p2 + p3);   // lane-local; reduce at end
            }
        }
        // ---- PV: each V b128 feeds 8 MFMAs (2 per q-subtile) --------------
        __builtin_amdgcn_s_setprio(1);
        #pragma unroll
        for (int kc8 = 0; kc8 < 2; ++kc8) {
            #pragma unroll
            for (int mt = 0; mt < 4; ++mt) {
                V8 vv;
                vv.v = *(const bf16x8*)&Vb[voff[kc8 * 4 + mt]];
                #pragma unroll
                for (int qs = 0; qs < 4; ++qs) {
                    cfr[qs][mt] = MFMA16K(vv.q[0], pk[qs][2 * kc8 + 0].s, cfr[qs][mt]);
                    cfr[qs][mt] = MFMA16K(vv.q[1], pk[qs][2 * kc8 + 1].s, cfr[qs][mt]);
                }
            }
        }
        __builtin_amdgcn_s_setprio(0);
    };

    // pipeline: stage issued right after barrier (full phase of flight),
    // drained by vmcnt(0) just before the next barrier.
    stage(0, 0);
    for (int h = 0; h < 8; ++h) {
        asm volatile("s_waitcnt vmcnt(0)" ::: "memory");
        __builtin_amdgcn_s_barrier();
        asm volatile("" ::: "memory");
        if (h < 7) stage(h + 1, (h + 1) & 1);
        tile_step(h & 1);
    }

    // all waves done with slots before reuse as transpose scratch
    __builtin_amdgcn_s_barrier();
    asm volatile("" ::: "memory");

    // epilogue: transpose ctx (64 rows/wave) through per-wave LDS region so
    // partial ctx goes out as coalesced bf16 16B stores.
    {
        __bf16* tb = (__bf16*)sbuf + w * 4352;     // 64 rows x stride 68
        #pragma unroll
        for (int qs = 0; qs < 4; ++qs)
            #pragma unroll
            for (int mt = 0; mt < 4; ++mt) {
                bf16x4 v;
                #pragma unroll
                for (int r = 0; r < 4; ++r) v[r] = (__bf16)cfr[qs][mt][r];
                *(bf16x4*)&tb[(qs * 16 + l15) * 68 + mt * 16 + quad * 4] = v;
            }
        const int rowbase = (split * 4 + b) * 4096 + l0 + w * 64;
        #pragma unroll
        for (int hh = 0; hh < 8; ++hh) {
            const int chunk = lane + hh * 64;      // 0..511
            const int tok = chunk >> 3, c8 = chunk & 7;
            bf16x8 v = *(const bf16x8*)&tb[tok * 68 + c8 * 8];
            *(bf16x8*)(Ops + (size_t)(rowbase + tok) * 64 + c8 * 8) = v;
        }
        #pragma unroll
        for (int qs = 0; qs < 4; ++qs) {
            float lr = l_acc[qs];
            lr += __shfl_xor(lr, 16);
            lr += __shfl_xor(lr, 32);
            if (quad == 0) Lws[rowbase + qs * 16 + l15] = lr;
        }
    }
}

// ---------------------------------------------------------------------------
// Kernel 3: split-combine + output projection + bias + residual.
// grid = 256 (b x 64 tiles of 64 tok). (byte-identical to round 5)
// ---------------------------------------------------------------------------
__global__ __launch_bounds__(256, 4) void outproj_kernel(
    const float* __restrict__ inpt,
    const __bf16* __restrict__ Ops, const float* __restrict__ Lws,
    const __bf16* __restrict__ Wo_b, const float* __restrict__ bo,
    float* __restrict__ out)
{
    __shared__ __align__(16) __bf16 cx[64 * 72];    // combined ctx [tok][d]
    const int bid = blockIdx.x;
    const int b   = bid >> 6;
    const int l0  = (bid & 63) << 6;
    const int t   = threadIdx.x;

    // combine: thread owns token = t>>2, four d16-groups (t&3)+4g.
    {
        const int token = t >> 2;
        const int rowb  = b * 4096 + l0 + token;
        float denom = 0.f;
        #pragma unroll
        for (int s = 0; s < SPLIT; ++s) denom += Lws[s * 16384 + rowb];
        const float inv = 1.f / denom;
        #pragma unroll
        for (int g = 0; g < 4; ++g) {
            const int d4 = (((t & 3) + g * 4)) << 2;
            float ax = 0.f, ay = 0.f, az = 0.f, aw = 0.f;
            #pragma unroll
            for (int s = 0; s < SPLIT; ++s) {
                const bf16x4 v = *(const bf16x4*)(Ops
                    + ((size_t)(s * 16384 + rowb)) * 64 + d4);
                ax += (float)v[0]; ay += (float)v[1];
                az += (float)v[2]; aw += (float)v[3];
            }
            bf16x4 pv;
            pv[0] = (__bf16)(ax * inv); pv[1] = (__bf16)(ay * inv);
            pv[2] = (__bf16)(az * inv); pv[3] = (__bf16)(aw * inv);
            *(bf16x4*)&cx[token * 72 + d4] = pv;
        }
    }
    __syncthreads();

    const int w    = t >> 6;
    const int lane = t & 63;
    const int quad = lane >> 4;
    const int l15  = lane & 15;

    f32x4 acc[2][4];
    #pragma unroll
    for (int mi = 0; mi < 2; ++mi)
        #pragma unroll
        for (int nt = 0; nt < 4; ++nt)
            #pragma unroll
            for (int r = 0; r < 4; ++r) acc[mi][nt][r] = 0.f;

    #pragma unroll
    for (int ks = 0; ks < 2; ++ks) {
        bf16x8 bfr[4];
        #pragma unroll
        for (int nt = 0; nt < 4; ++nt)
            bfr[nt] = *(const bf16x8*)&cx[(nt * 16 + l15) * 72 + ks * 32 + quad * 8];
        #pragma unroll
        for (int mi = 0; mi < 2; ++mi) {
            const int crow = (w * 2 + mi) * 16 + l15;
            bf16x8 af = *(const bf16x8*)(Wo_b + crow * 64 + ks * 32 + quad * 8);
            #pragma unroll
            for (int nt = 0; nt < 4; ++nt)
                acc[mi][nt] = MFMA32(af, bfr[nt], acc[mi][nt]);  // D[m=c][n=tok]
        }
    }

    // epilogue: rows (quad*4+r) = c offset, col l15 = token within subtile
    #pragma unroll
    for (int mi = 0; mi < 2; ++mi) {
        const int c0 = (w * 2 + mi) * 16 + quad * 4;
        #pragma unroll
        for (int nt = 0; nt < 4; ++nt) {
            #pragma unroll
            for (int r = 0; r < 4; ++r) {
                const int c = c0 + r;
                const size_t addr = ((size_t)(b * 128 + c)) * 4096
                                  + l0 + nt * 16 + l15;
                out[addr] = inpt[addr] + bo[c] + acc[mi][nt][r];
            }
        }
    }
}

// ---------------------------------------------------------------------------
extern "C" void kernel_launch(void* const* d_in, const int* in_sizes, int n_in,
                              void* d_out, int out_size, void* d_ws, size_t ws_size,
                              hipStream_t stream)
{
    const float* inpt = (const float*)d_in[0];
    const float* Wq   = (const float*)d_in[1];
    const float* bq   = (const float*)d_in[2];
    const float* Wk   = (const float*)d_in[3];
    const float* bk   = (const float*)d_in[4];
    const float* Wv   = (const float*)d_in[5];
    const float* bv   = (const float*)d_in[6];
    const float* Wo   = (const float*)d_in[7];
    const float* bo   = (const float*)d_in[8];
    float* out = (float*)d_out;

    char* ws = (char*)d_ws;
    const size_t MB = (size_t)1 << 20;
    __bf16* Qws    = (__bf16*)(ws + 0 * MB);
    __bf16* Kws    = (__bf16*)(ws + 2 * MB);       // MFMA-permuted tile layout
    __bf16* VTws   = (__bf16*)(ws + 4 * MB);       // permuted tile layout
    __bf16* Ops    = (__bf16*)(ws + 6 * MB);       // SPLIT(8) x 2.1MB
    float*  Lws    = (float*)(ws + 24 * MB);       // 512 KB
    __bf16* Wqkv_b = (__bf16*)(ws + 25 * MB);      // 48 KB
    __bf16* Wo_b   = (__bf16*)(ws + 25 * MB + (64 << 10));  // 16 KB

    wprep_kernel<<<32, 256, 0, stream>>>(Wq, Wk, Wv, Wo, Wqkv_b, Wo_b);
    qkv_kernel<<<256, 256, 0, stream>>>(inpt, bq, bk, bv, Wqkv_b, Qws, Kws, VTws);
    attn_kernel<<<SPLIT * 128, 128, 0, stream>>>(Qws, Kws, VTws, Ops, Lws);
    outproj_kernel<<<256, 256, 0, stream>>>(inpt, Ops, Lws, Wo_b, bo, out);
}

// Round 7
// 123.204 us; speedup vs baseline: 1.0014x; 1.0014x over previous
//
#include <hip/hip_runtime.h>
#include <hip/hip_bf16.h>

typedef __bf16 bf16x8 __attribute__((ext_vector_type(8)));
typedef __bf16 bf16x4 __attribute__((ext_vector_type(4)));
typedef short  s16x4  __attribute__((ext_vector_type(4)));
typedef float  f32x4  __attribute__((ext_vector_type(4)));

#define MFMA32(a, b, c) __builtin_amdgcn_mfma_f32_16x16x32_bf16((a), (b), (c), 0, 0, 0)
#define MFMA16K(a, b, c) __builtin_amdgcn_mfma_f32_16x16x16bf16_1k((a), (b), (c), 0, 0, 0)

#if __has_builtin(__builtin_amdgcn_exp2f)
#define EXP2F(x) __builtin_amdgcn_exp2f(x)
#else
#define EXP2F(x) __expf(0.6931471805599453f * (x))
#endif

// async global->LDS, 16B per lane. LDS dest must be wave-uniform base.
#define GL16(G, L)                                                            \
    __builtin_amdgcn_global_load_lds(                                         \
        (const __attribute__((address_space(1))) void*)(G),                   \
        (__attribute__((address_space(3))) void*)(L), 16, 0, 0)

#define SPLIT 8
// BS=4, C=128, L=4096, D=64. Q pre-scaled by 0.125*log2(e): softmax in base 2.
// Fixed-bound softmax: p = 2^(s - BBOUND); the 2^(m-B) factor cancels in the
// final normalization. BBOUND folded into QK MFMA accumulator init.
#define QSCALE 0.18033688011112042f
#define BBOUND 12.0f

// K workspace layout (MFMA-permuted, per 64-key tile contiguous 8 KB):
//   Kp[b][kt][nt][half][quad][l15][i]  (key = nt*16+l15, d = half*32+quad*8+i)
// V workspace layout (permuted, per 64-key tile contiguous 8 KB):
//   Vp[b][kt][d][quad][kc][i]  (quad=key>>2&3, kc=key>>4, i=key&3)

// ---------------------------------------------------------------------------
// Kernel 1: QKV projection, bf16 MFMA. grid = 512 (b x 128 tiles of 32 tok),
// 2 blocks/CU (vs 1 at round-5's 64-tok tiles) for latency hiding. Wave w
// owns (token-half tw = w&1, j-half jh = w>>1): 16 tokens x 6 n-tiles.
// Weights cast f32->bf16 inline (L1-shared across waves; no wprep kernel).
// ---------------------------------------------------------------------------
__global__ __launch_bounds__(256, 4) void qkv_kernel(
    const float* __restrict__ inpt,
    const float* __restrict__ Wq, const float* __restrict__ bq,
    const float* __restrict__ Wk, const float* __restrict__ bk,
    const float* __restrict__ Wv, const float* __restrict__ bv,
    __bf16* __restrict__ Qws, __bf16* __restrict__ Kws, __bf16* __restrict__ VTws)
{
    __shared__ __align__(16) __bf16 xT[32 * 136];   // [tok][c]
    __shared__ __align__(16) __bf16 os[32 * 136];   // [tok][qk-out 0..127]
    const int bid  = blockIdx.x;
    const int b    = bid >> 7;
    const int tile = bid & 127;
    const int l0   = tile << 5;                     // 32 tokens
    const int t    = threadIdx.x;

    // stage x^T: thread (c = t>>1, half = t&1) loads 16 floats of row c
    {
        const int c = t >> 1, half = t & 1;
        const float* xin = inpt + ((size_t)(b * 128 + c)) * 4096 + l0 + half * 16;
        #pragma unroll
        for (int i = 0; i < 4; ++i) {
            float4 v = *(const float4*)(xin + i * 4);
            const int tok = half * 16 + i * 4;
            xT[(tok + 0) * 136 + c] = (__bf16)v.x;
            xT[(tok + 1) * 136 + c] = (__bf16)v.y;
            xT[(tok + 2) * 136 + c] = (__bf16)v.z;
            xT[(tok + 3) * 136 + c] = (__bf16)v.w;
        }
    }
    __syncthreads();

    const int w    = t >> 6;
    const int lane = t & 63;
    const int quad = lane >> 4;
    const int l15  = lane & 15;
    const int tw   = w & 1;                         // token half (16 tok)
    const int jh   = w >> 1;                        // j half: j = jh*6 + jj

    f32x4 acc[6];
    #pragma unroll
    for (int jj = 0; jj < 6; ++jj)
        #pragma unroll
        for (int r = 0; r < 4; ++r) acc[jj][r] = 0.f;

    #pragma unroll
    for (int ks = 0; ks < 4; ++ks) {
        bf16x8 af = *(const bf16x8*)&xT[(tw * 16 + l15) * 136 + ks * 32 + quad * 8];
        #pragma unroll
        for (int jj = 0; jj < 6; ++jj) {
            const int j    = jh * 6 + jj;           // n-tile 0..11
            const int msel = j >> 2;                // 0=Q 1=K 2=V
            const float* W = (msel == 0) ? Wq : ((msel == 1) ? Wk : Wv);
            const float* Wp = W + ((j & 3) * 16 + l15) * 128 + ks * 32 + quad * 8;
            float4 wa = *(const float4*)Wp;
            float4 wb = *(const float4*)(Wp + 4);
            bf16x8 bf;
            bf[0] = (__bf16)wa.x; bf[1] = (__bf16)wa.y;
            bf[2] = (__bf16)wa.z; bf[3] = (__bf16)wa.w;
            bf[4] = (__bf16)wb.x; bf[5] = (__bf16)wb.y;
            bf[6] = (__bf16)wb.z; bf[7] = (__bf16)wb.w;
            acc[jj] = MFMA32(af, bf, acc[jj]);      // D[m=tok][n=out]
        }
    }

    // epilogue: D rows (quad*4+r) = token (within wave's 16), col l15 = out
    const int T16 = tile * 2 + tw;                  // global 16-token group
    #pragma unroll
    for (int jj = 0; jj < 6; ++jj) {
        const int j    = jh * 6 + jj;
        const int msel = j >> 2;
        const int o0   = (j & 3) * 16;
        const float* bb = (msel == 0) ? bq : ((msel == 1) ? bk : bv);
        float bias = bb[o0 + l15];
        if (msel < 2) {
            const float scl = (msel == 0) ? QSCALE : 1.0f;
            const int oc = j * 16 + l15;            // 0..127
            #pragma unroll
            for (int r = 0; r < 4; ++r)
                os[(tw * 16 + quad * 4 + r) * 136 + oc]
                    = (__bf16)((acc[jj][r] + bias) * scl);
        } else {
            // permuted V store: key = T16*16 + quad*4 + r -> kt = T16>>2,
            // kc = T16&3, quad_v = quad, i = r.
            const int d  = o0 + l15;
            const int kt = T16 >> 2;
            const int kc = T16 & 3;
            bf16x4 v;
            #pragma unroll
            for (int r = 0; r < 4; ++r) v[r] = (__bf16)(acc[jj][r] + bias);
            *(bf16x4*)(VTws + (size_t)b * 262144 + kt * 4096
                       + d * 64 + quad * 16 + kc * 4) = v;
        }
    }
    __syncthreads();

    // Q store coalesced [l][64]; K store to the MFMA-permuted tile layout.
    // 512 16B-chunks: chunk cid -> tok = cid>>4, c8 = cid&15 (c8<8 -> Q).
    #pragma unroll
    for (int g = 0; g < 2; ++g) {
        const int cid = t + g * 256;
        const int tok = cid >> 4, c8 = cid & 15;
        bf16x8 v = *(const bf16x8*)&os[tok * 136 + c8 * 8];
        if (c8 < 8) {
            *(bf16x8*)(Qws + ((size_t)(b * 4096 + l0 + tok)) * 64 + c8 * 8) = v;
        } else {
            const int d8   = c8 - 8;                // d = d8*8 .. +7
            const int KT16 = tile * 2 + (tok >> 4); // global 16-key group
            __bf16* dst = Kws + (size_t)b * 262144
                + (KT16 >> 2) * 4096          // tile
                + (KT16 & 3) * 1024           // nt subtile
                + (d8 >> 2) * 512             // half = d>>5
                + (d8 & 3) * 128              // quad = (d>>3)&3
                + (tok & 15) * 8;             // l15 = key&15
            *(bf16x8*)dst = v;
        }
    }
}

// ---------------------------------------------------------------------------
// Kernel 2: flash attention, split-K, fixed-bound softmax (no online max).
// Byte-identical to round 5 (the best measured build): 4-wave blocks, 32
// q-rows/wave (2 subtiles), K+V staged via global_load_lds into ring-2 LDS
// (32 KB), vmcnt(0)+s_barrier pipeline, XCD-chunked bid swizzle, setprio
// around PV MFMAs.
// grid = SPLIT x 128; block = 128 q (wave owns 32), 8 k-tiles of 64 keys.
// ---------------------------------------------------------------------------
__global__ __launch_bounds__(256, 4) void attn_kernel(
    const __bf16* __restrict__ Qws, const __bf16* __restrict__ Kws,
    const __bf16* __restrict__ VTws,
    __bf16* __restrict__ Ops, float* __restrict__ Lws)
{
    // [slot][0..4096) = K tile, [slot][4096..8192) = V tile
    __shared__ __align__(16) __bf16 sbuf[2][8192];

    const int bid0  = blockIdx.x;
    // XCD-chunked swizzle (bijective, 1024 % 8 == 0): XCD x owns split x.
    const int bid   = (bid0 & 7) * 128 + (bid0 >> 3);
    const int split = bid >> 7;
    const int qi    = bid & 127;
    const int b  = qi >> 5;
    const int l0 = (qi & 31) << 7;     // 128 q-rows per block
    const int t    = threadIdx.x;
    const int w    = t >> 6;
    const int lane = t & 63;
    const int quad = lane >> 4;
    const int l15  = lane & 15;

    // Q fragments for 2 subtiles (rows w*32 + qs*16 + l15), pre-scaled
    bf16x8 qf[2][2];
    #pragma unroll
    for (int qs = 0; qs < 2; ++qs) {
        const __bf16* qptr = Qws
            + ((size_t)(b * 4096 + l0 + w * 32 + qs * 16 + l15)) * 64 + quad * 8;
        qf[qs][0] = *(const bf16x8*)qptr;
        qf[qs][1] = *(const bf16x8*)(qptr + 32);
    }

    f32x4 cfr[2][4];
    #pragma unroll
    for (int qs = 0; qs < 2; ++qs)
        #pragma unroll
        for (int mt = 0; mt < 4; ++mt)
            #pragma unroll
            for (int r = 0; r < 4; ++r) cfr[qs][mt][r] = 0.f;
    float l_acc[2] = {0.f, 0.f};

    // hoisted V LDS element offsets (within V half of slot)
    int voff[8];
    #pragma unroll
    for (int mt = 0; mt < 4; ++mt) {
        const int d = mt * 16 + l15;
        #pragma unroll
        for (int kc8 = 0; kc8 < 2; ++kc8)
            voff[kc8 * 4 + mt] = d * 64 + (((2 * quad + kc8) ^ (d & 7)) * 8);
    }

    // staging source pointers (per-thread); LDS dests wave-uniform
    const uint4* Vg = (const uint4*)(VTws + ((size_t)b << 18));
    const int rw = t >> 3, cw = (t & 7) ^ ((t >> 3) & 7);
    const uint4* vbase = Vg + rw * 8 + cw + split * 4096;   // swizzled source
    const uint4* kbase = (const uint4*)(Kws + ((size_t)b << 18))
                       + t + split * 4096;                  // linear source

    union B4 { bf16x4 h; s16x4 s; };
    union V8 { bf16x8 v; s16x4 q[2]; };

    auto stage = [&](int kt, int slot) {                    // 4 GL16 / thread
        __bf16* Kd = &sbuf[slot][0];
        __bf16* Vd = &sbuf[slot][4096];
        const uint4* kp = kbase + kt * 512;
        const uint4* vp = vbase + kt * 512;
        GL16(kp,       Kd +        w * 512);
        GL16(kp + 256, Kd + 2048 + w * 512);
        GL16(vp,       Vd +        w * 512);
        GL16(vp + 256, Vd + 2048 + w * 512);
    };

    auto tile_step = [&](int slot) {
        const __bf16* Kb = &sbuf[slot][0];
        const __bf16* Vb = &sbuf[slot][4096];
        // ---- QK^T: K frags from LDS, shared across both q-subtiles -------
        B4 pk[2][4];
        #pragma unroll
        for (int nt = 0; nt < 4; ++nt) {
            bf16x8 k0 = *(const bf16x8*)(Kb + nt * 1024 +       lane * 8);
            bf16x8 k1 = *(const bf16x8*)(Kb + nt * 1024 + 512 + lane * 8);
            #pragma unroll
            for (int qs = 0; qs < 2; ++qs) {
                f32x4 a = {-BBOUND, -BBOUND, -BBOUND, -BBOUND};
                a = MFMA32(k0, qf[qs][0], a);
                a = MFMA32(k1, qf[qs][1], a);
                float p0 = EXP2F(a[0]), p1 = EXP2F(a[1]);
                float p2 = EXP2F(a[2]), p3 = EXP2F(a[3]);
                pk[qs][nt].h[0] = (__bf16)p0; pk[qs][nt].h[1] = (__bf16)p1;
                pk[qs][nt].h[2] = (__bf16)p2; pk[qs][nt].h[3] = (__bf16)p3;
                l_acc[qs] += (p0 + p1) + (p2 + p3);   // lane-local; reduce at end
            }
        }
        // ---- PV: each V b128 feeds 4 MFMAs (2 per q-subtile) --------------
        __builtin_amdgcn_s_setprio(1);
        #pragma unroll
        for (int kc8 = 0; kc8 < 2; ++kc8) {
            #pragma unroll
            for (int mt = 0; mt < 4; ++mt) {
                V8 vv;
                vv.v = *(const bf16x8*)&Vb[voff[kc8 * 4 + mt]];
                #pragma unroll
                for (int qs = 0; qs < 2; ++qs) {
                    cfr[qs][mt] = MFMA16K(vv.q[0], pk[qs][2 * kc8 + 0].s, cfr[qs][mt]);
                    cfr[qs][mt] = MFMA16K(vv.q[1], pk[qs][2 * kc8 + 1].s, cfr[qs][mt]);
                }
            }
        }
        __builtin_amdgcn_s_setprio(0);
    };

    // pipeline: stage issued right after barrier (full phase of flight),
    // drained by vmcnt(0) just before the next barrier.
    stage(0, 0);
    for (int h = 0; h < 8; ++h) {
        asm volatile("s_waitcnt vmcnt(0)" ::: "memory");
        __builtin_amdgcn_s_barrier();
        asm volatile("" ::: "memory");
        if (h < 7) stage(h + 1, (h + 1) & 1);
        tile_step(h & 1);
    }

    // all waves done with slots before reuse as transpose scratch
    __builtin_amdgcn_s_barrier();
    asm volatile("" ::: "memory");

    // epilogue: transpose ctx (32 rows/wave) through per-wave LDS region so
    // partial ctx goes out as coalesced bf16 16B stores.
    {
        __bf16* tb = (__bf16*)sbuf + w * 2176;     // 32 rows x stride 68
        #pragma unroll
        for (int qs = 0; qs < 2; ++qs)
            #pragma unroll
            for (int mt = 0; mt < 4; ++mt) {
                bf16x4 v;
                #pragma unroll
                for (int r = 0; r < 4; ++r) v[r] = (__bf16)cfr[qs][mt][r];
                *(bf16x4*)&tb[(qs * 16 + l15) * 68 + mt * 16 + quad * 4] = v;
            }
        const int rowbase = (split * 4 + b) * 4096 + l0 + w * 32;
        #pragma unroll
        for (int hh = 0; hh < 4; ++hh) {
            const int chunk = lane + hh * 64;      // 0..255
            const int tok = chunk >> 3, c8 = chunk & 7;
            bf16x8 v = *(const bf16x8*)&tb[tok * 68 + c8 * 8];
            *(bf16x8*)(Ops + (size_t)(rowbase + tok) * 64 + c8 * 8) = v;
        }
        #pragma unroll
        for (int qs = 0; qs < 2; ++qs) {
            float lr = l_acc[qs];
            lr += __shfl_xor(lr, 16);
            lr += __shfl_xor(lr, 32);
            if (quad == 0) Lws[rowbase + qs * 16 + l15] = lr;
        }
    }
}

// ---------------------------------------------------------------------------
// Kernel 3: split-combine + output projection + bias + residual.
// grid = 256 (b x 64 tiles of 64 tok). Wo cast f32->bf16 inline (L1-shared
// across waves/blocks; no wprep kernel). Each weight A-fragment reused
// across 4 token-subtiles.
// ---------------------------------------------------------------------------
__global__ __launch_bounds__(256, 4) void outproj_kernel(
    const float* __restrict__ inpt,
    const __bf16* __restrict__ Ops, const float* __restrict__ Lws,
    const float* __restrict__ Wo, const float* __restrict__ bo,
    float* __restrict__ out)
{
    __shared__ __align__(16) __bf16 cx[64 * 72];    // combined ctx [tok][d]
    const int bid = blockIdx.x;
    const int b   = bid >> 6;
    const int l0  = (bid & 63) << 6;
    const int t   = threadIdx.x;

    // combine: thread owns token = t>>2, four d16-groups (t&3)+4g.
    {
        const int token = t >> 2;
        const int rowb  = b * 4096 + l0 + token;
        float denom = 0.f;
        #pragma unroll
        for (int s = 0; s < SPLIT; ++s) denom += Lws[s * 16384 + rowb];
        const float inv = 1.f / denom;
        #pragma unroll
        for (int g = 0; g < 4; ++g) {
            const int d4 = (((t & 3) + g * 4)) << 2;
            float ax = 0.f, ay = 0.f, az = 0.f, aw = 0.f;
            #pragma unroll
            for (int s = 0; s < SPLIT; ++s) {
                const bf16x4 v = *(const bf16x4*)(Ops
                    + ((size_t)(s * 16384 + rowb)) * 64 + d4);
                ax += (float)v[0]; ay += (float)v[1];
                az += (float)v[2]; aw += (float)v[3];
            }
            bf16x4 pv;
            pv[0] = (__bf16)(ax * inv); pv[1] = (__bf16)(ay * inv);
            pv[2] = (__bf16)(az * inv); pv[3] = (__bf16)(aw * inv);
            *(bf16x4*)&cx[token * 72 + d4] = pv;
        }
    }
    __syncthreads();

    const int w    = t >> 6;
    const int lane = t & 63;
    const int quad = lane >> 4;
    const int l15  = lane & 15;

    f32x4 acc[2][4];
    #pragma unroll
    for (int mi = 0; mi < 2; ++mi)
        #pragma unroll
        for (int nt = 0; nt < 4; ++nt)
            #pragma unroll
            for (int r = 0; r < 4; ++r) acc[mi][nt][r] = 0.f;

    #pragma unroll
    for (int ks = 0; ks < 2; ++ks) {
        bf16x8 bfr[4];
        #pragma unroll
        for (int nt = 0; nt < 4; ++nt)
            bfr[nt] = *(const bf16x8*)&cx[(nt * 16 + l15) * 72 + ks * 32 + quad * 8];
        #pragma unroll
        for (int mi = 0; mi < 2; ++mi) {
            const int crow = (w * 2 + mi) * 16 + l15;
            const float* Wp = Wo + crow * 64 + ks * 32 + quad * 8;
            float4 wa = *(const float4*)Wp;
            float4 wb = *(const float4*)(Wp + 4);
            bf16x8 af;
            af[0] = (__bf16)wa.x; af[1] = (__bf16)wa.y;
            af[2] = (__bf16)wa.z; af[3] = (__bf16)wa.w;
            af[4] = (__bf16)wb.x; af[5] = (__bf16)wb.y;
            af[6] = (__bf16)wb.z; af[7] = (__bf16)wb.w;
            #pragma unroll
            for (int nt = 0; nt < 4; ++nt)
                acc[mi][nt] = MFMA32(af, bfr[nt], acc[mi][nt]);  // D[m=c][n=tok]
        }
    }

    // epilogue: rows (quad*4+r) = c offset, col l15 = token within subtile
    #pragma unroll
    for (int mi = 0; mi < 2; ++mi) {
        const int c0 = (w * 2 + mi) * 16 + quad * 4;
        #pragma unroll
        for (int nt = 0; nt < 4; ++nt) {
            #pragma unroll
            for (int r = 0; r < 4; ++r) {
                const int c = c0 + r;
                const size_t addr = ((size_t)(b * 128 + c)) * 4096
                                  + l0 + nt * 16 + l15;
                out[addr] = inpt[addr] + bo[c] + acc[mi][nt][r];
            }
        }
    }
}

// ---------------------------------------------------------------------------
extern "C" void kernel_launch(void* const* d_in, const int* in_sizes, int n_in,
                              void* d_out, int out_size, void* d_ws, size_t ws_size,
                              hipStream_t stream)
{
    const float* inpt = (const float*)d_in[0];
    const float* Wq   = (const float*)d_in[1];
    const float* bq   = (const float*)d_in[2];
    const float* Wk   = (const float*)d_in[3];
    const float* bk   = (const float*)d_in[4];
    const float* Wv   = (const float*)d_in[5];
    const float* bv   = (const float*)d_in[6];
    const float* Wo   = (const float*)d_in[7];
    const float* bo   = (const float*)d_in[8];
    float* out = (float*)d_out;

    char* ws = (char*)d_ws;
    const size_t MB = (size_t)1 << 20;
    __bf16* Qws    = (__bf16*)(ws + 0 * MB);
    __bf16* Kws    = (__bf16*)(ws + 2 * MB);       // MFMA-permuted tile layout
    __bf16* VTws   = (__bf16*)(ws + 4 * MB);       // permuted tile layout
    __bf16* Ops    = (__bf16*)(ws + 6 * MB);       // SPLIT(8) x 2.1MB
    float*  Lws    = (float*)(ws + 24 * MB);       // 512 KB

    qkv_kernel<<<512, 256, 0, stream>>>(inpt, Wq, bq, Wk, bk, Wv, bv,
                                        Qws, Kws, VTws);
    attn_kernel<<<SPLIT * 128, 256, 0, stream>>>(Qws, Kws, VTws, Ops, Lws);
    outproj_kernel<<<256, 256, 0, stream>>>(inpt, Ops, Lws, Wo, bo, out);
}

// Round 8
// 117.992 us; speedup vs baseline: 1.0457x; 1.0442x over previous
//
#include <hip/hip_runtime.h>
#include <hip/hip_bf16.h>

typedef __bf16 bf16x8 __attribute__((ext_vector_type(8)));
typedef __bf16 bf16x4 __attribute__((ext_vector_type(4)));
typedef short  s16x4  __attribute__((ext_vector_type(4)));
typedef float  f32x4  __attribute__((ext_vector_type(4)));

#define MFMA32(a, b, c) __builtin_amdgcn_mfma_f32_16x16x32_bf16((a), (b), (c), 0, 0, 0)
#define MFMA16K(a, b, c) __builtin_amdgcn_mfma_f32_16x16x16bf16_1k((a), (b), (c), 0, 0, 0)

#if __has_builtin(__builtin_amdgcn_exp2f)
#define EXP2F(x) __builtin_amdgcn_exp2f(x)
#else
#define EXP2F(x) __expf(0.6931471805599453f * (x))
#endif

// async global->LDS, 16B per lane. LDS dest must be wave-uniform base.
#define GL16(G, L)                                                            \
    __builtin_amdgcn_global_load_lds(                                         \
        (const __attribute__((address_space(1))) void*)(G),                   \
        (__attribute__((address_space(3))) void*)(L), 16, 0, 0)

#define SPLIT 8
// BS=4, C=128, L=4096, D=64. Q pre-scaled by 0.125*log2(e): softmax in base 2.
// Fixed-bound softmax: p = 2^(s - BBOUND); the 2^(m-B) factor cancels in the
// final normalization. BBOUND folded into QK MFMA accumulator init.
#define QSCALE 0.18033688011112042f
#define BBOUND 12.0f

// K workspace layout (MFMA-permuted, per 64-key tile contiguous 8 KB):
//   Kp[b][kt][nt][half][quad][l15][i]  (key = nt*16+l15, d = half*32+quad*8+i)
// V workspace layout (permuted, per 64-key tile contiguous 8 KB):
//   Vp[b][kt][d][quad][kc][i]  (quad=key>>2&3, kc=key>>4, i=key&3)
// Wqkv_b: [msel][64][128] bf16 row-major (linear cast of Wq|Wk|Wv)
// Wo_b:   [128][64] bf16 row-major (linear cast of Wo)

// ---------------------------------------------------------------------------
// Kernel 0: one-time weight cast f32 -> bf16 (linear copy). 32768 elements.
// (byte-identical to round 5)
// ---------------------------------------------------------------------------
__global__ __launch_bounds__(256) void wprep_kernel(
    const float* __restrict__ Wq, const float* __restrict__ Wk,
    const float* __restrict__ Wv, const float* __restrict__ Wo,
    __bf16* __restrict__ Wqkv_b, __bf16* __restrict__ Wo_b)
{
    const int idx = (blockIdx.x * 256 + threadIdx.x) * 4;   // 32 blocks
    const float* src;
    __bf16* dst;
    if (idx < 8192)       { src = Wq + idx;         dst = Wqkv_b + idx; }
    else if (idx < 16384) { src = Wk + idx - 8192;  dst = Wqkv_b + idx; }
    else if (idx < 24576) { src = Wv + idx - 16384; dst = Wqkv_b + idx; }
    else                  { src = Wo + idx - 24576; dst = Wo_b + idx - 24576; }
    float4 v = *(const float4*)src;
    bf16x4 o;
    o[0] = (__bf16)v.x; o[1] = (__bf16)v.y;
    o[2] = (__bf16)v.z; o[3] = (__bf16)v.w;
    *(bf16x4*)dst = o;
}

// ---------------------------------------------------------------------------
// Kernel 1: QKV projection, bf16 MFMA. grid = 256 (b x 64 tiles of 64 tok).
// (byte-identical to round 5)
// ---------------------------------------------------------------------------
__global__ __launch_bounds__(256, 4) void qkv_kernel(
    const float* __restrict__ inpt,
    const float* __restrict__ bq, const float* __restrict__ bk,
    const float* __restrict__ bv,
    const __bf16* __restrict__ Wqkv_b,
    __bf16* __restrict__ Qws, __bf16* __restrict__ Kws, __bf16* __restrict__ VTws)
{
    __shared__ __align__(16) __bf16 xT[64 * 136];   // [tok][c]
    __shared__ __align__(16) __bf16 os[64 * 136];   // [tok][qk-out 0..127]
    const int bid = blockIdx.x;
    const int b   = bid >> 6;
    const int l0  = (bid & 63) << 6;                // 64 tokens
    const int t   = threadIdx.x;

    // stage x^T: thread (c = t>>1, half = t&1) loads 32 floats of row c
    {
        const int c = t >> 1, half = t & 1;
        const float* xin = inpt + ((size_t)(b * 128 + c)) * 4096 + l0 + half * 32;
        #pragma unroll
        for (int i = 0; i < 8; ++i) {
            float4 v = *(const float4*)(xin + i * 4);
            const int tok = half * 32 + i * 4;
            xT[(tok + 0) * 136 + c] = (__bf16)v.x;
            xT[(tok + 1) * 136 + c] = (__bf16)v.y;
            xT[(tok + 2) * 136 + c] = (__bf16)v.z;
            xT[(tok + 3) * 136 + c] = (__bf16)v.w;
        }
    }
    __syncthreads();

    const int w    = t >> 6;
    const int lane = t & 63;
    const int quad = lane >> 4;
    const int l15  = lane & 15;

    f32x4 acc[12];
    #pragma unroll
    for (int j = 0; j < 12; ++j)
        #pragma unroll
        for (int r = 0; r < 4; ++r) acc[j][r] = 0.f;

    #pragma unroll
    for (int ks = 0; ks < 4; ++ks) {
        bf16x8 af = *(const bf16x8*)&xT[(w * 16 + l15) * 136 + ks * 32 + quad * 8];
        #pragma unroll
        for (int j = 0; j < 12; ++j) {
            bf16x8 bf = *(const bf16x8*)(Wqkv_b + j * 2048 + l15 * 128
                                         + ks * 32 + quad * 8);
            acc[j] = MFMA32(af, bf, acc[j]);        // D[m=tok][n=out]
        }
    }

    // epilogue: D rows (quad*4+r) = token (within wave's 16), col l15 = out
    #pragma unroll
    for (int j = 0; j < 12; ++j) {
        const int msel = j >> 2;
        const int o0   = (j & 3) * 16;
        const float* bb = (msel == 0) ? bq : ((msel == 1) ? bk : bv);
        float bias = bb[o0 + l15];
        if (msel < 2) {
            const float scl = (msel == 0) ? QSCALE : 1.0f;
            const int oc = j * 16 + l15;            // 0..127
            #pragma unroll
            for (int r = 0; r < 4; ++r)
                os[(w * 16 + quad * 4 + r) * 136 + oc]
                    = (__bf16)((acc[j][r] + bias) * scl);
        } else {
            // permuted V store: key = w*16 + quad*4 + r within the block's
            // single 64-key tile -> kc = w, quad_v = quad, i = r.
            const int d  = o0 + l15;
            const int kt = bid & 63;
            bf16x4 v;
            #pragma unroll
            for (int r = 0; r < 4; ++r) v[r] = (__bf16)(acc[j][r] + bias);
            *(bf16x4*)(VTws + (size_t)b * 262144 + kt * 4096
                       + d * 64 + quad * 16 + w * 4) = v;
        }
    }
    __syncthreads();

    // Q store coalesced [l][64]; K store to the MFMA-permuted tile layout.
    // 1024 16B-chunks: chunk cid -> tok = cid>>4, c8 = cid&15 (c8<8 -> Q).
    #pragma unroll
    for (int g = 0; g < 4; ++g) {
        const int cid = t + g * 256;
        const int tok = cid >> 4, c8 = cid & 15;
        bf16x8 v = *(const bf16x8*)&os[tok * 136 + c8 * 8];
        if (c8 < 8) {
            *(bf16x8*)(Qws + ((size_t)(b * 4096 + l0 + tok)) * 64 + c8 * 8) = v;
        } else {
            const int d8 = c8 - 8;                  // d = d8*8 .. +7
            __bf16* dst = Kws + (size_t)b * 262144
                + (bid & 63) * 4096           // tile
                + (tok >> 4) * 1024           // nt subtile
                + (d8 >> 2) * 512             // half = d>>5
                + (d8 & 3) * 128              // quad = (d>>3)&3
                + (tok & 15) * 8;             // l15 = key&15
            *(bf16x8*)dst = v;
        }
    }
}

// ---------------------------------------------------------------------------
// Kernel 2: flash attention, split-K, fixed-bound softmax (no online max).
// NEW this round: 512-thread blocks (8 waves x 32 q-rows = 256 q-rows per
// block). Per-wave inner code identical to round 5; each staged 16 KB K/V
// tile now serves 2x the output -> total K/V fragment traffic through L2/L3
// halves (134 -> 67 MB). Occupancy unchanged: 2 blocks/CU x 8 waves = 16
// waves/CU (same as r5's 4 x 4). Ring-2 K+V LDS (36 KB incl. epilogue pad),
// vmcnt(0)+s_barrier pipeline, XCD-chunked bid swizzle, setprio around PV.
// grid = SPLIT x 64; block = 256 q (wave owns 32), 8 k-tiles of 64 keys.
// ---------------------------------------------------------------------------
__global__ __launch_bounds__(512, 2) void attn_kernel(
    const __bf16* __restrict__ Qws, const __bf16* __restrict__ Kws,
    const __bf16* __restrict__ VTws,
    __bf16* __restrict__ Ops, float* __restrict__ Lws)
{
    // [slot][0..4096) = K tile, [slot][4096..8192) = V tile, rest = pad so
    // the 8-wave epilogue transpose (8 x 2176 elems) fits.
    __shared__ __align__(16) __bf16 sbuf[2][9216];

    const int bid0  = blockIdx.x;
    // XCD-chunked swizzle (bijective, 512 % 8 == 0): XCD x owns split x.
    const int bid   = (bid0 & 7) * 64 + (bid0 >> 3);
    const int split = bid >> 6;
    const int qi    = bid & 63;
    const int b  = qi >> 4;
    const int l0 = (qi & 15) << 8;     // 256 q-rows per block
    const int t    = threadIdx.x;
    const int w    = t >> 6;           // wave 0..7
    const int lane = t & 63;
    const int quad = lane >> 4;
    const int l15  = lane & 15;

    // Q fragments for 2 subtiles (rows l0 + w*32 + qs*16 + l15), pre-scaled
    bf16x8 qf[2][2];
    #pragma unroll
    for (int qs = 0; qs < 2; ++qs) {
        const __bf16* qptr = Qws
            + ((size_t)(b * 4096 + l0 + w * 32 + qs * 16 + l15)) * 64 + quad * 8;
        qf[qs][0] = *(const bf16x8*)qptr;
        qf[qs][1] = *(const bf16x8*)(qptr + 32);
    }

    f32x4 cfr[2][4];
    #pragma unroll
    for (int qs = 0; qs < 2; ++qs)
        #pragma unroll
        for (int mt = 0; mt < 4; ++mt)
            #pragma unroll
            for (int r = 0; r < 4; ++r) cfr[qs][mt][r] = 0.f;
    float l_acc[2] = {0.f, 0.f};

    // hoisted V LDS element offsets (within V half of slot)
    int voff[8];
    #pragma unroll
    for (int mt = 0; mt < 4; ++mt) {
        const int d = mt * 16 + l15;
        #pragma unroll
        for (int kc8 = 0; kc8 < 2; ++kc8)
            voff[kc8 * 4 + mt] = d * 64 + (((2 * quad + kc8) ^ (d & 7)) * 8);
    }

    // staging source pointers (per-thread); LDS dests wave-uniform.
    // 512 threads cover one 8 KB tile (512 x 16B) in a single GL16 each.
    const uint4* Vg = (const uint4*)(VTws + ((size_t)b << 18));
    const int rw = t >> 3, cw = (t & 7) ^ ((t >> 3) & 7);
    const uint4* vbase = Vg + rw * 8 + cw + split * 4096;   // swizzled source
    const uint4* kbase = (const uint4*)(Kws + ((size_t)b << 18))
                       + t + split * 4096;                  // linear source

    union B4 { bf16x4 h; s16x4 s; };
    union V8 { bf16x8 v; s16x4 q[2]; };

    auto stage = [&](int kt, int slot) {                    // 2 GL16 / thread
        __bf16* Kd = &sbuf[slot][0];
        __bf16* Vd = &sbuf[slot][4096];
        GL16(kbase + kt * 512, Kd + w * 512);
        GL16(vbase + kt * 512, Vd + w * 512);
    };

    auto tile_step = [&](int slot) {
        const __bf16* Kb = &sbuf[slot][0];
        const __bf16* Vb = &sbuf[slot][4096];
        // ---- QK^T: K frags from LDS, shared across both q-subtiles -------
        B4 pk[2][4];
        #pragma unroll
        for (int nt = 0; nt < 4; ++nt) {
            bf16x8 k0 = *(const bf16x8*)(Kb + nt * 1024 +       lane * 8);
            bf16x8 k1 = *(const bf16x8*)(Kb + nt * 1024 + 512 + lane * 8);
            #pragma unroll
            for (int qs = 0; qs < 2; ++qs) {
                f32x4 a = {-BBOUND, -BBOUND, -BBOUND, -BBOUND};
                a = MFMA32(k0, qf[qs][0], a);
                a = MFMA32(k1, qf[qs][1], a);
                float p0 = EXP2F(a[0]), p1 = EXP2F(a[1]);
                float p2 = EXP2F(a[2]), p3 = EXP2F(a[3]);
                pk[qs][nt].h[0] = (__bf16)p0; pk[qs][nt].h[1] = (__bf16)p1;
                pk[qs][nt].h[2] = (__bf16)p2; pk[qs][nt].h[3] = (__bf16)p3;
                l_acc[qs] += (p0 + p1) + (p2 + p3);   // lane-local; reduce at end
            }
        }
        // ---- PV: each V b128 feeds 4 MFMAs (2 per q-subtile) --------------
        __builtin_amdgcn_s_setprio(1);
        #pragma unroll
        for (int kc8 = 0; kc8 < 2; ++kc8) {
            #pragma unroll
            for (int mt = 0; mt < 4; ++mt) {
                V8 vv;
                vv.v = *(const bf16x8*)&Vb[voff[kc8 * 4 + mt]];
                #pragma unroll
                for (int qs = 0; qs < 2; ++qs) {
                    cfr[qs][mt] = MFMA16K(vv.q[0], pk[qs][2 * kc8 + 0].s, cfr[qs][mt]);
                    cfr[qs][mt] = MFMA16K(vv.q[1], pk[qs][2 * kc8 + 1].s, cfr[qs][mt]);
                }
            }
        }
        __builtin_amdgcn_s_setprio(0);
    };

    // pipeline: stage issued right after barrier (full phase of flight),
    // drained by vmcnt(0) just before the next barrier.
    stage(0, 0);
    for (int h = 0; h < 8; ++h) {
        asm volatile("s_waitcnt vmcnt(0)" ::: "memory");
        __builtin_amdgcn_s_barrier();
        asm volatile("" ::: "memory");
        if (h < 7) stage(h + 1, (h + 1) & 1);
        tile_step(h & 1);
    }

    // all waves done with slots before reuse as transpose scratch
    __builtin_amdgcn_s_barrier();
    asm volatile("" ::: "memory");

    // epilogue: transpose ctx (32 rows/wave) through per-wave LDS region so
    // partial ctx goes out as coalesced bf16 16B stores.
    {
        __bf16* tb = (__bf16*)sbuf + w * 2176;     // 32 rows x stride 68
        #pragma unroll
        for (int qs = 0; qs < 2; ++qs)
            #pragma unroll
            for (int mt = 0; mt < 4; ++mt) {
                bf16x4 v;
                #pragma unroll
                for (int r = 0; r < 4; ++r) v[r] = (__bf16)cfr[qs][mt][r];
                *(bf16x4*)&tb[(qs * 16 + l15) * 68 + mt * 16 + quad * 4] = v;
            }
        const int rowbase = (split * 4 + b) * 4096 + l0 + w * 32;
        #pragma unroll
        for (int hh = 0; hh < 4; ++hh) {
            const int chunk = lane + hh * 64;      // 0..255
            const int tok = chunk >> 3, c8 = chunk & 7;
            bf16x8 v = *(const bf16x8*)&tb[tok * 68 + c8 * 8];
            *(bf16x8*)(Ops + (size_t)(rowbase + tok) * 64 + c8 * 8) = v;
        }
        #pragma unroll
        for (int qs = 0; qs < 2; ++qs) {
            float lr = l_acc[qs];
            lr += __shfl_xor(lr, 16);
            lr += __shfl_xor(lr, 32);
            if (quad == 0) Lws[rowbase + qs * 16 + l15] = lr;
        }
    }
}

// ---------------------------------------------------------------------------
// Kernel 3: split-combine + output projection + bias + residual.
// grid = 256 (b x 64 tiles of 64 tok). (byte-identical to round 5)
// ---------------------------------------------------------------------------
__global__ __launch_bounds__(256, 4) void outproj_kernel(
    const float* __restrict__ inpt,
    const __bf16* __restrict__ Ops, const float* __restrict__ Lws,
    const __bf16* __restrict__ Wo_b, const float* __restrict__ bo,
    float* __restrict__ out)
{
    __shared__ __align__(16) __bf16 cx[64 * 72];    // combined ctx [tok][d]
    const int bid = blockIdx.x;
    const int b   = bid >> 6;
    const int l0  = (bid & 63) << 6;
    const int t   = threadIdx.x;

    // combine: thread owns token = t>>2, four d16-groups (t&3)+4g.
    {
        const int token = t >> 2;
        const int rowb  = b * 4096 + l0 + token;
        float denom = 0.f;
        #pragma unroll
        for (int s = 0; s < SPLIT; ++s) denom += Lws[s * 16384 + rowb];
        const float inv = 1.f / denom;
        #pragma unroll
        for (int g = 0; g < 4; ++g) {
            const int d4 = (((t & 3) + g * 4)) << 2;
            float ax = 0.f, ay = 0.f, az = 0.f, aw = 0.f;
            #pragma unroll
            for (int s = 0; s < SPLIT; ++s) {
                const bf16x4 v = *(const bf16x4*)(Ops
                    + ((size_t)(s * 16384 + rowb)) * 64 + d4);
                ax += (float)v[0]; ay += (float)v[1];
                az += (float)v[2]; aw += (float)v[3];
            }
            bf16x4 pv;
            pv[0] = (__bf16)(ax * inv); pv[1] = (__bf16)(ay * inv);
            pv[2] = (__bf16)(az * inv); pv[3] = (__bf16)(aw * inv);
            *(bf16x4*)&cx[token * 72 + d4] = pv;
        }
    }
    __syncthreads();

    const int w    = t >> 6;
    const int lane = t & 63;
    const int quad = lane >> 4;
    const int l15  = lane & 15;

    f32x4 acc[2][4];
    #pragma unroll
    for (int mi = 0; mi < 2; ++mi)
        #pragma unroll
        for (int nt = 0; nt < 4; ++nt)
            #pragma unroll
            for (int r = 0; r < 4; ++r) acc[mi][nt][r] = 0.f;

    #pragma unroll
    for (int ks = 0; ks < 2; ++ks) {
        bf16x8 bfr[4];
        #pragma unroll
        for (int nt = 0; nt < 4; ++nt)
            bfr[nt] = *(const bf16x8*)&cx[(nt * 16 + l15) * 72 + ks * 32 + quad * 8];
        #pragma unroll
        for (int mi = 0; mi < 2; ++mi) {
            const int crow = (w * 2 + mi) * 16 + l15;
            bf16x8 af = *(const bf16x8*)(Wo_b + crow * 64 + ks * 32 + quad * 8);
            #pragma unroll
            for (int nt = 0; nt < 4; ++nt)
                acc[mi][nt] = MFMA32(af, bfr[nt], acc[mi][nt]);  // D[m=c][n=tok]
        }
    }

    // epilogue: rows (quad*4+r) = c offset, col l15 = token within subtile
    #pragma unroll
    for (int mi = 0; mi < 2; ++mi) {
        const int c0 = (w * 2 + mi) * 16 + quad * 4;
        #pragma unroll
        for (int nt = 0; nt < 4; ++nt) {
            #pragma unroll
            for (int r = 0; r < 4; ++r) {
                const int c = c0 + r;
                const size_t addr = ((size_t)(b * 128 + c)) * 4096
                                  + l0 + nt * 16 + l15;
                out[addr] = inpt[addr] + bo[c] + acc[mi][nt][r];
            }
        }
    }
}

// ---------------------------------------------------------------------------
extern "C" void kernel_launch(void* const* d_in, const int* in_sizes, int n_in,
                              void* d_out, int out_size, void* d_ws, size_t ws_size,
                              hipStream_t stream)
{
    const float* inpt = (const float*)d_in[0];
    const float* Wq   = (const float*)d_in[1];
    const float* bq   = (const float*)d_in[2];
    const float* Wk   = (const float*)d_in[3];
    const float* bk   = (const float*)d_in[4];
    const float* Wv   = (const float*)d_in[5];
    const float* bv   = (const float*)d_in[6];
    const float* Wo   = (const float*)d_in[7];
    const float* bo   = (const float*)d_in[8];
    float* out = (float*)d_out;

    char* ws = (char*)d_ws;
    const size_t MB = (size_t)1 << 20;
    __bf16* Qws    = (__bf16*)(ws + 0 * MB);
    __bf16* Kws    = (__bf16*)(ws + 2 * MB);       // MFMA-permuted tile layout
    __bf16* VTws   = (__bf16*)(ws + 4 * MB);       // permuted tile layout
    __bf16* Ops    = (__bf16*)(ws + 6 * MB);       // SPLIT(8) x 2.1MB
    float*  Lws    = (float*)(ws + 24 * MB);       // 512 KB
    __bf16* Wqkv_b = (__bf16*)(ws + 25 * MB);      // 48 KB
    __bf16* Wo_b   = (__bf16*)(ws + 25 * MB + (64 << 10));  // 16 KB

    wprep_kernel<<<32, 256, 0, stream>>>(Wq, Wk, Wv, Wo, Wqkv_b, Wo_b);
    qkv_kernel<<<256, 256, 0, stream>>>(inpt, bq, bk, bv, Wqkv_b, Qws, Kws, VTws);
    attn_kernel<<<SPLIT * 64, 512, 0, stream>>>(Qws, Kws, VTws, Ops, Lws);
    outproj_kernel<<<256, 256, 0, stream>>>(inpt, Ops, Lws, Wo_b, bo, out);
}